// Round 8
// baseline (462.892 us; speedup 1.0000x reference)
//
#include <hip/hip_runtime.h>
#include <math.h>

#define N_TOKENS 4096
#define D_MODEL  1024
#define N_EXPERT 8
#define D_HIDDEN 1024
#define N_POS    8192   // N_TOKENS * TOP_K

typedef __bf16 bf16x8 __attribute__((ext_vector_type(8)));
typedef float  f32x4  __attribute__((ext_vector_type(4)));
typedef unsigned short u16x8 __attribute__((ext_vector_type(8)));

#define GLOBAL_AS __attribute__((address_space(1)))
#define LDS_AS    __attribute__((address_space(3)))

static __device__ __forceinline__ void async_ld16(const void* g, void* l) {
    __builtin_amdgcn_global_load_lds((GLOBAL_AS void*)g, (LDS_AS void*)l, 16, 0, 0);
}

static __device__ __forceinline__ unsigned short f2bf(float f) {
    unsigned int u = __builtin_bit_cast(unsigned int, f);
    u += 0x7fffu + ((u >> 16) & 1u);      // round-to-nearest-even
    return (unsigned short)(u >> 16);
}
static __device__ __forceinline__ unsigned int pack2(float a, float b) {
    return (unsigned int)f2bf(a) | ((unsigned int)f2bf(b) << 16);
}
static __device__ __forceinline__ float bflo(unsigned int u) {
    return __builtin_bit_cast(float, u << 16);
}
static __device__ __forceinline__ float bfhi(unsigned int u) {
    return __builtin_bit_cast(float, u & 0xffff0000u);
}

// ---------------------------------------------------------------------------
// fp32 -> bf16 transposed weight convert. src [K][N] -> dst [N][K] k-contig.
// Also zeroes cnts (replaces the hipMemsetAsync graph node).
// ---------------------------------------------------------------------------
__global__ __launch_bounds__(256) void convert_transpose_kernel(
    const float* __restrict__ w1, const float* __restrict__ w2,
    unsigned short* __restrict__ w1b, unsigned short* __restrict__ w2b,
    int* __restrict__ cnts)
{
    int tid = threadIdx.x;
    if (blockIdx.x == 0 && blockIdx.y == 0 && blockIdx.z == 0 && tid < 8)
        cnts[tid] = 0;
    int mat = blockIdx.z;   // 0..7: w1 experts, 8..15: w2 experts
    const float* src = (mat < 8) ? (w1 + (size_t)mat * 1048576)
                                 : (w2 + (size_t)(mat - 8) * 1048576);
    unsigned short* dst = (mat < 8) ? (w1b + (size_t)mat * 1048576)
                                    : (w2b + (size_t)(mat - 8) * 1048576);
    __shared__ float tile[64][68];
    int r0 = blockIdx.x * 64, c0 = blockIdx.y * 64;
    #pragma unroll
    for (int i = 0; i < 4; ++i) {
        int r = (tid >> 4) + i * 16;
        float4 v = *(const float4*)(src + (size_t)(r0 + r) * 1024 + c0 + (tid & 15) * 4);
        *(float4*)&tile[r][(tid & 15) * 4] = v;
    }
    __syncthreads();
    int dr = tid >> 2;                     // dst row in tile (= src col)
    #pragma unroll
    for (int p = 0; p < 2; ++p) {
        int ch = (tid & 3) + p * 4;        // 8-elem chunk of the 64 src rows
        u16x8 o;
        #pragma unroll
        for (int j = 0; j < 8; ++j) o[j] = f2bf(tile[ch * 8 + j][dr]);
        *(u16x8*)(dst + (size_t)(c0 + dr) * 1024 + r0 + ch * 8) = o;
    }
}

// ---------------------------------------------------------------------------
// Gate: fp32-exact top-2 + softmax. Block-aggregated ranking.
// ---------------------------------------------------------------------------
__global__ __launch_bounds__(256) void gate_kernel(
    const float* __restrict__ inp, const float* __restrict__ gate_w,
    const float* __restrict__ gate_b, int* __restrict__ cnts,
    int* __restrict__ emeta, float* __restrict__ stok)
{
    __shared__ int bcnt[8], base[8];
    __shared__ int tinfo[16];   // e0 | e1<<4 | r0<<8 | r1<<20 (block-local)
    int tid = threadIdx.x, lane = tid & 63, wave = tid >> 6;
    if (tid < 8) bcnt[tid] = 0;
    __syncthreads();

    for (int t = 0; t < 4; ++t) {
        int ti = wave * 4 + t;
        int n  = blockIdx.x * 16 + ti;
        const float* ip = inp + (size_t)n * D_MODEL;
        float acc[8] = {0.f,0.f,0.f,0.f,0.f,0.f,0.f,0.f};
        for (int d0 = lane * 4; d0 < D_MODEL; d0 += 256) {
            float4 x = *(const float4*)(ip + d0);
            #pragma unroll
            for (int j = 0; j < 4; ++j) {
                float xv = (j == 0) ? x.x : (j == 1) ? x.y : (j == 2) ? x.z : x.w;
                float4 g0 = *(const float4*)(gate_w + (d0 + j) * 8);
                float4 g1 = *(const float4*)(gate_w + (d0 + j) * 8 + 4);
                acc[0] += xv * g0.x; acc[1] += xv * g0.y;
                acc[2] += xv * g0.z; acc[3] += xv * g0.w;
                acc[4] += xv * g1.x; acc[5] += xv * g1.y;
                acc[6] += xv * g1.z; acc[7] += xv * g1.w;
            }
        }
        #pragma unroll
        for (int off = 32; off > 0; off >>= 1)
            #pragma unroll
            for (int e = 0; e < 8; ++e)
                acc[e] += __shfl_xor(acc[e], off, 64);
        #pragma unroll
        for (int e = 0; e < 8; ++e) acc[e] += gate_b[e];

        // top-2; strictly-greater => lowest index wins ties (lax.top_k)
        int e0 = 0; float v0 = acc[0];
        #pragma unroll
        for (int e = 1; e < 8; ++e) if (acc[e] > v0) { v0 = acc[e]; e0 = e; }
        int e1 = -1; float v1 = -1e30f;
        #pragma unroll
        for (int e = 0; e < 8; ++e) if (e != e0 && acc[e] > v1) { v1 = acc[e]; e1 = e; }
        float tv = expf(v1 - v0);
        float s0 = 1.0f / (1.0f + tv);
        float s1 = tv / (1.0f + tv);

        if (lane == 0) {
            int r0 = atomicAdd(&bcnt[e0], 1);   // LDS atomic: block-local rank
            int r1 = atomicAdd(&bcnt[e1], 1);
            tinfo[ti] = e0 | (e1 << 4) | (r0 << 8) | (r1 << 20);
            stok[2 * n]     = s0;
            stok[2 * n + 1] = s1;
        }
    }
    __syncthreads();
    if (tid < 8) base[tid] = atomicAdd(&cnts[tid], bcnt[tid]);  // 8 globals/block
    __syncthreads();
    if (tid < 16) {
        int n = blockIdx.x * 16 + tid;
        unsigned int inf = (unsigned int)tinfo[tid];
        int e0 = inf & 15, e1 = (inf >> 4) & 15;
        int p0 = base[e0] + ((inf >> 8) & 4095);
        int p1 = base[e1] + (int)(inf >> 20);
        emeta[n] = e0 | (e1 << 4) | (p0 << 8) | (p1 << 20);
    }
}

// ---------------------------------------------------------------------------
// Gather: expert-sorted bf16 activation matrix Ag[N_POS][D_MODEL] (in d_out)
// + token -> position map.
// ---------------------------------------------------------------------------
__global__ __launch_bounds__(256) void gather_kernel(
    const float* __restrict__ inp, const int* __restrict__ cnts,
    const int* __restrict__ emeta, unsigned short* __restrict__ Ag,
    int* __restrict__ tok2pos)
{
    int lane = threadIdx.x & 63, wave = threadIdx.x >> 6;
    int n = blockIdx.x * 4 + wave;
    unsigned int em = (unsigned int)emeta[n];
    int e0 = em & 15, e1 = (em >> 4) & 15;
    int p0 = (em >> 8) & 4095, p1 = (int)(em >> 20);
    int off0 = 0, off1 = 0;
    #pragma unroll
    for (int e = 0; e < 8; ++e) {
        int c = cnts[e];
        off0 += (e < e0) ? c : 0;
        off1 += (e < e1) ? c : 0;
    }
    int pos0 = off0 + p0, pos1 = off1 + p1;
    if (lane == 0) {
        tok2pos[2 * n]     = pos0;
        tok2pos[2 * n + 1] = pos1;
    }
    const float* ip = inp + (size_t)n * D_MODEL;
    unsigned short* r0 = Ag + (size_t)pos0 * D_MODEL;
    unsigned short* r1 = Ag + (size_t)pos1 * D_MODEL;
    for (int d = lane * 4; d < D_MODEL; d += 256) {
        float4 v = *(const float4*)(ip + d);
        uint2 u; u.x = pack2(v.x, v.y); u.y = pack2(v.z, v.w);
        *(uint2*)(r0 + d) = u;
        *(uint2*)(r1 + d) = u;
    }
}

// ---------------------------------------------------------------------------
// Grouped GEMM, R8 structure (barrier-free K-loop):
//  - B-slice [64 cols][1024 k] staged in LDS ONCE (128 KB, chunk-XOR swizzle),
//    single __syncthreads after staging; Bs is read-only thereafter.
//  - A fragments load global->register (per-lane dwordx4, one 64B line per
//    quad-group) with explicit depth-1 prefetch; compiler emits fine-grained
//    vmcnt(N) — no barrier drain (the R6/R7 structural stall).
//  - 512-thread block (8 waves), wave = 64 rows x 64 cols, 1 block/CU.
//  - grid 256: e = bid&7 pins expert to one XCD (L2 locality for A re-reads).
// ---------------------------------------------------------------------------
template <bool GELU>
__device__ __forceinline__ void ffn_gemm(
    const unsigned short* __restrict__ A, const unsigned short* __restrict__ Bw,
    const float* __restrict__ bias, const int* __restrict__ cnts,
    unsigned short* __restrict__ Out)
{
    int bid = blockIdx.x;
    int e = bid & 7, nt = (bid >> 3) & 15, ms = bid >> 7;   // ms in {0,1}
    int off = 0, Ne = 0;
    #pragma unroll
    for (int i = 0; i < 8; ++i) {
        int c = cnts[i];
        off += (i < e) ? c : 0;
        Ne = (i == e) ? c : Ne;
    }
    int n0 = nt * 64;

    __shared__ unsigned short Bs[64 * 1024];   // [col][k-chunk swizzled] 128 KB

    int tid = threadIdx.x, lane = tid & 63, wave = tid >> 6;   // 8 waves
    int lane15 = lane & 15, quad = lane >> 4;

    // ---- stage Bs: 128 x 1KB global_load_lds, slot s of col holds chunk
    // cc = s ^ (col&7)  (bank-spread for the fragment reads below) ----
    const unsigned short* bsrc = Bw + (size_t)e * 1024 * 1024;
    #pragma unroll
    for (int t = 0; t < 16; ++t) {
        int idx = wave * 16 + t;              // 0..127
        int col = idx >> 1;
        int sbase = (idx & 1) * 64;
        int cc = (sbase + lane) ^ (col & 7);
        async_ld16(bsrc + (size_t)(n0 + col) * 1024 + cc * 8,
                   &Bs[(size_t)(col * 128 + sbase) * 8]);
    }
    __syncthreads();   // the ONLY barrier

    float bv[4];
    if (GELU) {
        #pragma unroll
        for (int j = 0; j < 4; ++j)
            bv[j] = bias[e * 1024 + n0 + j * 16 + lane15];
    }

    // ---- m-chunks: wave handles chunks g = ms*8+wave (+16 per round) ----
    for (int g = ms * 8 + wave; g * 64 < Ne; g += 16) {
        const unsigned short* ap[4];
        #pragma unroll
        for (int i = 0; i < 4; ++i) {
            int rr = g * 64 + i * 16 + lane15;
            if (rr >= Ne) rr = Ne - 1;            // clamp; masked at store
            ap[i] = A + (size_t)(off + rr) * 1024 + quad * 8;
        }

        f32x4 acc[4][4] = {};
        bf16x8 av[4], bw[4];
        #pragma unroll
        for (int i = 0; i < 4; ++i) av[i] = *(const bf16x8*)(ap[i]);
        #pragma unroll
        for (int j = 0; j < 4; ++j) {
            int col = j * 16 + lane15;
            bw[j] = *(const bf16x8*)&Bs[col * 1024 + ((quad ^ (col & 7)) << 3)];
        }

        for (int k0 = 0; k0 < 1024; k0 += 32) {
            bf16x8 an[4], bn[4];
            bool more = (k0 + 32) < 1024;
            if (more) {
                #pragma unroll
                for (int i = 0; i < 4; ++i)
                    an[i] = *(const bf16x8*)(ap[i] + k0 + 32);
                #pragma unroll
                for (int j = 0; j < 4; ++j) {
                    int col = j * 16 + lane15;
                    int cc = ((k0 + 32) >> 3) + quad;
                    bn[j] = *(const bf16x8*)
                        &Bs[col * 1024 + ((cc ^ (col & 7)) << 3)];
                }
            }
            #pragma unroll
            for (int i = 0; i < 4; ++i)
                #pragma unroll
                for (int j = 0; j < 4; ++j)
                    acc[i][j] = __builtin_amdgcn_mfma_f32_16x16x32_bf16(
                        av[i], bw[j], acc[i][j], 0, 0, 0);
            if (more) {
                #pragma unroll
                for (int i = 0; i < 4; ++i) av[i] = an[i];
                #pragma unroll
                for (int j = 0; j < 4; ++j) bw[j] = bn[j];
            }
        }

        // epilogue
        #pragma unroll
        for (int j = 0; j < 4; ++j) {
            int gcol = n0 + j * 16 + lane15;
            #pragma unroll
            for (int i = 0; i < 4; ++i) {
                int rowb = g * 64 + i * 16 + quad * 4;
                #pragma unroll
                for (int r = 0; r < 4; ++r) {
                    int row = rowb + r;
                    if (row < Ne) {
                        float x = acc[i][j][r];
                        if (GELU) {
                            x += bv[j];
                            x = 0.5f * x * (1.0f + erff(x * 0.70710678118654752f));
                        }
                        Out[(size_t)(off + row) * 1024 + gcol] = f2bf(x);
                    }
                }
            }
        }
    }
}

__global__ __launch_bounds__(512, 2) void ffn1_kernel(
    const unsigned short* __restrict__ Ag, const unsigned short* __restrict__ w1b,
    const float* __restrict__ b1, const int* __restrict__ cnts,
    unsigned short* __restrict__ Hg)
{
    ffn_gemm<true>(Ag, w1b, b1, cnts, Hg);
}

__global__ __launch_bounds__(512, 2) void ffn2_kernel(
    const unsigned short* __restrict__ Hg, const unsigned short* __restrict__ w2b,
    const int* __restrict__ cnts, unsigned short* __restrict__ Og)
{
    ffn_gemm<false>(Hg, w2b, nullptr, cnts, Og);
}

// ---------------------------------------------------------------------------
// Combine: out[n] = s0*(Og[pos0]+b2[e0]) + s1*(Og[pos1]+b2[e1])
// ---------------------------------------------------------------------------
__global__ __launch_bounds__(256) void combine_kernel(
    const unsigned short* __restrict__ Og, const int* __restrict__ tok2pos,
    const float* __restrict__ stok, const int* __restrict__ emeta,
    const float* __restrict__ b2, float* __restrict__ out)
{
    int lane = threadIdx.x & 63, wave = threadIdx.x >> 6;
    int n = blockIdx.x * 4 + wave;
    int pos0 = tok2pos[2 * n], pos1 = tok2pos[2 * n + 1];
    float s0 = stok[2 * n], s1 = stok[2 * n + 1];
    unsigned int em = (unsigned int)emeta[n];
    int e0 = em & 15, e1 = (em >> 4) & 15;
    const unsigned short* o0 = Og + (size_t)pos0 * D_MODEL;
    const unsigned short* o1 = Og + (size_t)pos1 * D_MODEL;
    const float* bA = b2 + (size_t)e0 * D_MODEL;
    const float* bB = b2 + (size_t)e1 * D_MODEL;
    float* op = out + (size_t)n * D_MODEL;
    for (int d = lane * 4; d < D_MODEL; d += 256) {
        uint2 u0 = *(const uint2*)(o0 + d);
        uint2 u1 = *(const uint2*)(o1 + d);
        float4 xa = *(const float4*)(bA + d);
        float4 xb = *(const float4*)(bB + d);
        float4 r;
        r.x = s0 * (bflo(u0.x) + xa.x) + s1 * (bflo(u1.x) + xb.x);
        r.y = s0 * (bfhi(u0.x) + xa.y) + s1 * (bfhi(u1.x) + xb.y);
        r.z = s0 * (bflo(u0.y) + xa.z) + s1 * (bflo(u1.y) + xb.z);
        r.w = s0 * (bfhi(u0.y) + xa.w) + s1 * (bfhi(u1.y) + xb.w);
        *(float4*)(op + d) = r;
    }
}

// ---------------------------------------------------------------------------
extern "C" void kernel_launch(void* const* d_in, const int* in_sizes, int n_in,
                              void* d_out, int out_size, void* d_ws, size_t ws_size,
                              hipStream_t stream) {
    const float* inp    = (const float*)d_in[0];
    const float* gate_w = (const float*)d_in[1];
    const float* gate_b = (const float*)d_in[2];
    const float* w1     = (const float*)d_in[3];
    const float* b1     = (const float*)d_in[4];
    const float* w2     = (const float*)d_in[5];
    const float* b2     = (const float*)d_in[6];
    float* out = (float*)d_out;

    // ws layout (Og aliases w1b: w1b dead after ffn1, Og written in ffn2).
    char* ws = (char*)d_ws;
    int*   cnts    = (int*)  (ws);                               // 128 B
    int*   emeta   = (int*)  (ws + 4096);                        // 16 KB
    float* stok    = (float*)(ws + 65536);                       // 32 KB
    int*   tok2pos = (int*)  (ws + 131072);                      // 32 KB
    unsigned short* w2b = (unsigned short*)(ws + 1048576);       // 16 MiB
    unsigned short* Hg  = (unsigned short*)(ws + 17825792);      // 16 MiB
    unsigned short* w1b = (unsigned short*)(ws + 34603008);      // 16 MiB
    unsigned short* Og  = (unsigned short*)(ws + 34603008);      // aliases w1b

    // Ag (expert-sorted bf16 activations) lives in d_out (16 MiB); d_out is
    // rewritten by combine_kernel at the end.
    unsigned short* Ag = (unsigned short*)d_out;

    convert_transpose_kernel<<<dim3(16, 16, 16), 256, 0, stream>>>(
        w1, w2, w1b, w2b, cnts);
    gate_kernel<<<dim3(N_TOKENS / 16), 256, 0, stream>>>(
        inp, gate_w, gate_b, cnts, emeta, stok);
    gather_kernel<<<dim3(N_TOKENS / 4), 256, 0, stream>>>(
        inp, cnts, emeta, Ag, tok2pos);
    ffn1_kernel<<<dim3(256), 512, 0, stream>>>(Ag, w1b, b1, cnts, Hg);
    ffn2_kernel<<<dim3(256), 512, 0, stream>>>(Hg, w2b, cnts, Og);
    combine_kernel<<<dim3(N_TOKENS / 4), 256, 0, stream>>>(
        Og, tok2pos, stok, emeta, b2, out);
}

// Round 9
// 231.099 us; speedup vs baseline: 2.0030x; 2.0030x over previous
//
#include <hip/hip_runtime.h>
#include <math.h>

#define N_TOKENS 4096
#define D_MODEL  1024
#define N_EXPERT 8
#define D_HIDDEN 1024
#define N_POS    8192   // N_TOKENS * TOP_K

typedef __bf16 bf16x8 __attribute__((ext_vector_type(8)));
typedef float  f32x4  __attribute__((ext_vector_type(4)));
typedef unsigned short u16x8 __attribute__((ext_vector_type(8)));

#define GLOBAL_AS __attribute__((address_space(1)))
#define LDS_AS    __attribute__((address_space(3)))

static __device__ __forceinline__ void async_ld16(const void* g, void* l) {
    __builtin_amdgcn_global_load_lds((GLOBAL_AS void*)g, (LDS_AS void*)l, 16, 0, 0);
}

static __device__ __forceinline__ unsigned short f2bf(float f) {
    unsigned int u = __builtin_bit_cast(unsigned int, f);
    u += 0x7fffu + ((u >> 16) & 1u);      // round-to-nearest-even
    return (unsigned short)(u >> 16);
}
static __device__ __forceinline__ unsigned int pack2(float a, float b) {
    return (unsigned int)f2bf(a) | ((unsigned int)f2bf(b) << 16);
}
static __device__ __forceinline__ float bflo(unsigned int u) {
    return __builtin_bit_cast(float, u << 16);
}
static __device__ __forceinline__ float bfhi(unsigned int u) {
    return __builtin_bit_cast(float, u & 0xffff0000u);
}

// ---------------------------------------------------------------------------
// fp32 -> bf16 transposed weight convert. src [K][N] -> dst [N][K] k-contig.
// Also zeroes cnts (replaces the hipMemsetAsync graph node).
// ---------------------------------------------------------------------------
__global__ __launch_bounds__(256) void convert_transpose_kernel(
    const float* __restrict__ w1, const float* __restrict__ w2,
    unsigned short* __restrict__ w1b, unsigned short* __restrict__ w2b,
    int* __restrict__ cnts)
{
    int tid = threadIdx.x;
    if (blockIdx.x == 0 && blockIdx.y == 0 && blockIdx.z == 0 && tid < 8)
        cnts[tid] = 0;
    int mat = blockIdx.z;   // 0..7: w1 experts, 8..15: w2 experts
    const float* src = (mat < 8) ? (w1 + (size_t)mat * 1048576)
                                 : (w2 + (size_t)(mat - 8) * 1048576);
    unsigned short* dst = (mat < 8) ? (w1b + (size_t)mat * 1048576)
                                    : (w2b + (size_t)(mat - 8) * 1048576);
    __shared__ float tile[64][68];
    int r0 = blockIdx.x * 64, c0 = blockIdx.y * 64;
    #pragma unroll
    for (int i = 0; i < 4; ++i) {
        int r = (tid >> 4) + i * 16;
        float4 v = *(const float4*)(src + (size_t)(r0 + r) * 1024 + c0 + (tid & 15) * 4);
        *(float4*)&tile[r][(tid & 15) * 4] = v;
    }
    __syncthreads();
    int dr = tid >> 2;                     // dst row in tile (= src col)
    #pragma unroll
    for (int p = 0; p < 2; ++p) {
        int ch = (tid & 3) + p * 4;        // 8-elem chunk of the 64 src rows
        u16x8 o;
        #pragma unroll
        for (int j = 0; j < 8; ++j) o[j] = f2bf(tile[ch * 8 + j][dr]);
        *(u16x8*)(dst + (size_t)(c0 + dr) * 1024 + r0 + ch * 8) = o;
    }
}

// ---------------------------------------------------------------------------
// Gate: fp32-exact top-2 + softmax. Block-aggregated ranking.
// ---------------------------------------------------------------------------
__global__ __launch_bounds__(256) void gate_kernel(
    const float* __restrict__ inp, const float* __restrict__ gate_w,
    const float* __restrict__ gate_b, int* __restrict__ cnts,
    int* __restrict__ emeta, float* __restrict__ stok)
{
    __shared__ int bcnt[8], base[8];
    __shared__ int tinfo[16];   // e0 | e1<<4 | r0<<8 | r1<<20 (block-local)
    int tid = threadIdx.x, lane = tid & 63, wave = tid >> 6;
    if (tid < 8) bcnt[tid] = 0;
    __syncthreads();

    for (int t = 0; t < 4; ++t) {
        int ti = wave * 4 + t;
        int n  = blockIdx.x * 16 + ti;
        const float* ip = inp + (size_t)n * D_MODEL;
        float acc[8] = {0.f,0.f,0.f,0.f,0.f,0.f,0.f,0.f};
        for (int d0 = lane * 4; d0 < D_MODEL; d0 += 256) {
            float4 x = *(const float4*)(ip + d0);
            #pragma unroll
            for (int j = 0; j < 4; ++j) {
                float xv = (j == 0) ? x.x : (j == 1) ? x.y : (j == 2) ? x.z : x.w;
                float4 g0 = *(const float4*)(gate_w + (d0 + j) * 8);
                float4 g1 = *(const float4*)(gate_w + (d0 + j) * 8 + 4);
                acc[0] += xv * g0.x; acc[1] += xv * g0.y;
                acc[2] += xv * g0.z; acc[3] += xv * g0.w;
                acc[4] += xv * g1.x; acc[5] += xv * g1.y;
                acc[6] += xv * g1.z; acc[7] += xv * g1.w;
            }
        }
        #pragma unroll
        for (int off = 32; off > 0; off >>= 1)
            #pragma unroll
            for (int e = 0; e < 8; ++e)
                acc[e] += __shfl_xor(acc[e], off, 64);
        #pragma unroll
        for (int e = 0; e < 8; ++e) acc[e] += gate_b[e];

        // top-2; strictly-greater => lowest index wins ties (lax.top_k)
        int e0 = 0; float v0 = acc[0];
        #pragma unroll
        for (int e = 1; e < 8; ++e) if (acc[e] > v0) { v0 = acc[e]; e0 = e; }
        int e1 = -1; float v1 = -1e30f;
        #pragma unroll
        for (int e = 0; e < 8; ++e) if (e != e0 && acc[e] > v1) { v1 = acc[e]; e1 = e; }
        float tv = expf(v1 - v0);
        float s0 = 1.0f / (1.0f + tv);
        float s1 = tv / (1.0f + tv);

        if (lane == 0) {
            int r0 = atomicAdd(&bcnt[e0], 1);   // LDS atomic: block-local rank
            int r1 = atomicAdd(&bcnt[e1], 1);
            tinfo[ti] = e0 | (e1 << 4) | (r0 << 8) | (r1 << 20);
            stok[2 * n]     = s0;
            stok[2 * n + 1] = s1;
        }
    }
    __syncthreads();
    if (tid < 8) base[tid] = atomicAdd(&cnts[tid], bcnt[tid]);  // 8 globals/block
    __syncthreads();
    if (tid < 16) {
        int n = blockIdx.x * 16 + tid;
        unsigned int inf = (unsigned int)tinfo[tid];
        int e0 = inf & 15, e1 = (inf >> 4) & 15;
        int p0 = base[e0] + ((inf >> 8) & 4095);
        int p1 = base[e1] + (int)(inf >> 20);
        emeta[n] = e0 | (e1 << 4) | (p0 << 8) | (p1 << 20);
    }
}

// ---------------------------------------------------------------------------
// Gather: expert-sorted bf16 activation matrix Ag[N_POS][D_MODEL] (in d_out)
// + token -> position map.
// ---------------------------------------------------------------------------
__global__ __launch_bounds__(256) void gather_kernel(
    const float* __restrict__ inp, const int* __restrict__ cnts,
    const int* __restrict__ emeta, unsigned short* __restrict__ Ag,
    int* __restrict__ tok2pos)
{
    int lane = threadIdx.x & 63, wave = threadIdx.x >> 6;
    int n = blockIdx.x * 4 + wave;
    unsigned int em = (unsigned int)emeta[n];
    int e0 = em & 15, e1 = (em >> 4) & 15;
    int p0 = (em >> 8) & 4095, p1 = (int)(em >> 20);
    int off0 = 0, off1 = 0;
    #pragma unroll
    for (int e = 0; e < 8; ++e) {
        int c = cnts[e];
        off0 += (e < e0) ? c : 0;
        off1 += (e < e1) ? c : 0;
    }
    int pos0 = off0 + p0, pos1 = off1 + p1;
    if (lane == 0) {
        tok2pos[2 * n]     = pos0;
        tok2pos[2 * n + 1] = pos1;
    }
    const float* ip = inp + (size_t)n * D_MODEL;
    unsigned short* r0 = Ag + (size_t)pos0 * D_MODEL;
    unsigned short* r1 = Ag + (size_t)pos1 * D_MODEL;
    for (int d = lane * 4; d < D_MODEL; d += 256) {
        float4 v = *(const float4*)(ip + d);
        uint2 u; u.x = pack2(v.x, v.y); u.y = pack2(v.z, v.w);
        *(uint2*)(r0 + d) = u;
        *(uint2*)(r1 + d) = u;
    }
}

// ---------------------------------------------------------------------------
// Grouped GEMM1: Hg[pos] = gelu( Ag[pos] @ w1b[e]^T + b1[e] )
// R9: R6 structure (128x64 tile, single-buffer, all-async staging, per-lane
// source-row clamp) with BK 64->128: K-loop 16->8 iters, halving the number
// of vmcnt(0)+barrier drains (the structural stall; bytes unchanged).
// LDS 48 KB -> 3 blocks/CU. Fragments processed per-32k half (regs reused).
// ---------------------------------------------------------------------------
__global__ __launch_bounds__(256, 3) void ffn1_kernel(
    const unsigned short* __restrict__ Ag, const unsigned short* __restrict__ w1b,
    const float* __restrict__ b1, const int* __restrict__ cnts,
    unsigned short* __restrict__ Hg)
{
    int bid = blockIdx.x;
    int e = bid & 7, nt = (bid >> 3) & 15, mt = bid >> 7;
    int off = 0, Ne = 0;
    #pragma unroll
    for (int i = 0; i < 8; ++i) {
        int c = cnts[i];
        off += (i < e) ? c : 0;
        Ne = (i == e) ? c : Ne;
    }
    int m0 = mt * 128;
    if (m0 >= Ne) return;
    int n0 = nt * 64;

    __shared__ unsigned short As[4 * 128 * 32];   // [kchunk][row][32] 32 KB
    __shared__ unsigned short Bs[4 * 64 * 32];    // [kchunk][row][32] 16 KB

    int tid = threadIdx.x, lane = tid & 63, wave = tid >> 6;
    int lrow = lane >> 2, lchunk = lane & 3;
    int csw8 = (lchunk ^ ((lrow >> 1) & 3)) * 8;

    int ga0 = off + m0 + wave * 32 + lrow;        // per-lane global source row
    int ga1 = ga0 + 16;
    if (ga0 >= N_POS) ga0 = N_POS - 1;            // rows >= segment end are
    if (ga1 >= N_POS) ga1 = N_POS - 1;            // masked in the epilogue
    const unsigned short* aS0 = Ag + (size_t)ga0 * D_MODEL + csw8;
    const unsigned short* aS1 = Ag + (size_t)ga1 * D_MODEL + csw8;
    const unsigned short* bS = w1b + (size_t)e * D_MODEL * D_HIDDEN
                             + (size_t)(n0 + wave * 16 + lrow) * D_MODEL + csw8;
    unsigned short* aD0 = &As[(wave * 32) * 32];
    unsigned short* aD1 = &As[(wave * 32 + 16) * 32];
    unsigned short* bD  = &Bs[(wave * 16) * 32];

    f32x4 acc[4][2] = {};
    int wm = (wave & 1) * 64, wn = ((wave >> 1) & 1) * 32;
    int lane15 = lane & 15, quad = lane >> 4;
    int fro = (quad ^ ((lane15 >> 1) & 3)) * 8;

    for (int k0 = 0; k0 < D_MODEL; k0 += 128) {
        #pragma unroll
        for (int h = 0; h < 4; ++h) {
            int ko = k0 + h * 32;
            async_ld16(aS0 + ko, aD0 + h * 4096);
            async_ld16(aS1 + ko, aD1 + h * 4096);
            async_ld16(bS  + ko, bD  + h * 2048);
        }
        __syncthreads();
        #pragma unroll
        for (int h = 0; h < 4; ++h) {
            bf16x8 af[4], bf[2];
            #pragma unroll
            for (int t = 0; t < 4; ++t)
                af[t] = *(const bf16x8*)&As[h * 4096 + (wm + t * 16 + lane15) * 32 + fro];
            #pragma unroll
            for (int t = 0; t < 2; ++t)
                bf[t] = *(const bf16x8*)&Bs[h * 2048 + (wn + t * 16 + lane15) * 32 + fro];
            #pragma unroll
            for (int i = 0; i < 4; ++i)
                #pragma unroll
                for (int j = 0; j < 2; ++j)
                    acc[i][j] = __builtin_amdgcn_mfma_f32_16x16x32_bf16(
                        af[i], bf[j], acc[i][j], 0, 0, 0);
        }
        if (k0 + 128 < D_MODEL) __syncthreads();
    }

    const float* bexp = b1 + (size_t)e * D_HIDDEN;
    #pragma unroll
    for (int j = 0; j < 2; ++j) {
        int gcol = n0 + wn + j * 16 + lane15;
        float bv = bexp[gcol];
        #pragma unroll
        for (int i = 0; i < 4; ++i) {
            int rowb = wm + i * 16 + quad * 4;
            #pragma unroll
            for (int r = 0; r < 4; ++r) {
                int row = rowb + r;
                if (m0 + row < Ne) {
                    float x = acc[i][j][r] + bv;
                    float gv = 0.5f * x * (1.0f + erff(x * 0.70710678118654752f));
                    Hg[(size_t)(off + m0 + row) * D_HIDDEN + gcol] = f2bf(gv);
                }
            }
        }
    }
}

// ---------------------------------------------------------------------------
// Grouped GEMM2: Og[pos] = Hg[pos] @ w2b[e]^T  (same BK=128 128x64 structure)
// ---------------------------------------------------------------------------
__global__ __launch_bounds__(256, 3) void ffn2_kernel(
    const unsigned short* __restrict__ Hg, const unsigned short* __restrict__ w2b,
    const int* __restrict__ cnts, unsigned short* __restrict__ Og)
{
    int bid = blockIdx.x;
    int e = bid & 7, nt = (bid >> 3) & 15, mt = bid >> 7;
    int off = 0, Ne = 0;
    #pragma unroll
    for (int i = 0; i < 8; ++i) {
        int c = cnts[i];
        off += (i < e) ? c : 0;
        Ne = (i == e) ? c : Ne;
    }
    int m0 = mt * 128;
    if (m0 >= Ne) return;
    int n0 = nt * 64;

    __shared__ unsigned short As[4 * 128 * 32];
    __shared__ unsigned short Bs[4 * 64 * 32];

    int tid = threadIdx.x, lane = tid & 63, wave = tid >> 6;
    int lrow = lane >> 2, lchunk = lane & 3;
    int csw8 = (lchunk ^ ((lrow >> 1) & 3)) * 8;

    int ga0 = off + m0 + wave * 32 + lrow;
    int ga1 = ga0 + 16;
    if (ga0 >= N_POS) ga0 = N_POS - 1;
    if (ga1 >= N_POS) ga1 = N_POS - 1;
    const unsigned short* aS0 = Hg + (size_t)ga0 * D_HIDDEN + csw8;
    const unsigned short* aS1 = Hg + (size_t)ga1 * D_HIDDEN + csw8;
    const unsigned short* bS = w2b + (size_t)e * D_HIDDEN * D_MODEL
                             + (size_t)(n0 + wave * 16 + lrow) * D_HIDDEN + csw8;
    unsigned short* aD0 = &As[(wave * 32) * 32];
    unsigned short* aD1 = &As[(wave * 32 + 16) * 32];
    unsigned short* bD  = &Bs[(wave * 16) * 32];

    f32x4 acc[4][2] = {};
    int wm = (wave & 1) * 64, wn = ((wave >> 1) & 1) * 32;
    int lane15 = lane & 15, quad = lane >> 4;
    int fro = (quad ^ ((lane15 >> 1) & 3)) * 8;

    for (int k0 = 0; k0 < D_HIDDEN; k0 += 128) {
        #pragma unroll
        for (int h = 0; h < 4; ++h) {
            int ko = k0 + h * 32;
            async_ld16(aS0 + ko, aD0 + h * 4096);
            async_ld16(aS1 + ko, aD1 + h * 4096);
            async_ld16(bS  + ko, bD  + h * 2048);
        }
        __syncthreads();
        #pragma unroll
        for (int h = 0; h < 4; ++h) {
            bf16x8 af[4], bf[2];
            #pragma unroll
            for (int t = 0; t < 4; ++t)
                af[t] = *(const bf16x8*)&As[h * 4096 + (wm + t * 16 + lane15) * 32 + fro];
            #pragma unroll
            for (int t = 0; t < 2; ++t)
                bf[t] = *(const bf16x8*)&Bs[h * 2048 + (wn + t * 16 + lane15) * 32 + fro];
            #pragma unroll
            for (int i = 0; i < 4; ++i)
                #pragma unroll
                for (int j = 0; j < 2; ++j)
                    acc[i][j] = __builtin_amdgcn_mfma_f32_16x16x32_bf16(
                        af[i], bf[j], acc[i][j], 0, 0, 0);
        }
        if (k0 + 128 < D_HIDDEN) __syncthreads();
    }

    #pragma unroll
    for (int j = 0; j < 2; ++j) {
        int gcol = n0 + wn + j * 16 + lane15;
        #pragma unroll
        for (int i = 0; i < 4; ++i) {
            int rowb = wm + i * 16 + quad * 4;
            #pragma unroll
            for (int r = 0; r < 4; ++r) {
                int row = rowb + r;
                if (m0 + row < Ne) {
                    Og[(size_t)(off + m0 + row) * D_MODEL + gcol] =
                        f2bf(acc[i][j][r]);
                }
            }
        }
    }
}

// ---------------------------------------------------------------------------
// Combine: out[n] = s0*(Og[pos0]+b2[e0]) + s1*(Og[pos1]+b2[e1])
// ---------------------------------------------------------------------------
__global__ __launch_bounds__(256) void combine_kernel(
    const unsigned short* __restrict__ Og, const int* __restrict__ tok2pos,
    const float* __restrict__ stok, const int* __restrict__ emeta,
    const float* __restrict__ b2, float* __restrict__ out)
{
    int lane = threadIdx.x & 63, wave = threadIdx.x >> 6;
    int n = blockIdx.x * 4 + wave;
    int pos0 = tok2pos[2 * n], pos1 = tok2pos[2 * n + 1];
    float s0 = stok[2 * n], s1 = stok[2 * n + 1];
    unsigned int em = (unsigned int)emeta[n];
    int e0 = em & 15, e1 = (em >> 4) & 15;
    const unsigned short* o0 = Og + (size_t)pos0 * D_MODEL;
    const unsigned short* o1 = Og + (size_t)pos1 * D_MODEL;
    const float* bA = b2 + (size_t)e0 * D_MODEL;
    const float* bB = b2 + (size_t)e1 * D_MODEL;
    float* op = out + (size_t)n * D_MODEL;
    for (int d = lane * 4; d < D_MODEL; d += 256) {
        uint2 u0 = *(const uint2*)(o0 + d);
        uint2 u1 = *(const uint2*)(o1 + d);
        float4 xa = *(const float4*)(bA + d);
        float4 xb = *(const float4*)(bB + d);
        float4 r;
        r.x = s0 * (bflo(u0.x) + xa.x) + s1 * (bflo(u1.x) + xb.x);
        r.y = s0 * (bfhi(u0.x) + xa.y) + s1 * (bfhi(u1.x) + xb.y);
        r.z = s0 * (bflo(u0.y) + xa.z) + s1 * (bflo(u1.y) + xb.z);
        r.w = s0 * (bfhi(u0.y) + xa.w) + s1 * (bfhi(u1.y) + xb.w);
        *(float4*)(op + d) = r;
    }
}

// ---------------------------------------------------------------------------
extern "C" void kernel_launch(void* const* d_in, const int* in_sizes, int n_in,
                              void* d_out, int out_size, void* d_ws, size_t ws_size,
                              hipStream_t stream) {
    const float* inp    = (const float*)d_in[0];
    const float* gate_w = (const float*)d_in[1];
    const float* gate_b = (const float*)d_in[2];
    const float* w1     = (const float*)d_in[3];
    const float* b1     = (const float*)d_in[4];
    const float* w2     = (const float*)d_in[5];
    const float* b2     = (const float*)d_in[6];
    float* out = (float*)d_out;

    // ws layout (Og aliases w1b: w1b dead after ffn1, Og written in ffn2).
    char* ws = (char*)d_ws;
    int*   cnts    = (int*)  (ws);                               // 128 B
    int*   emeta   = (int*)  (ws + 4096);                        // 16 KB
    float* stok    = (float*)(ws + 65536);                       // 32 KB
    int*   tok2pos = (int*)  (ws + 131072);                      // 32 KB
    unsigned short* w2b = (unsigned short*)(ws + 1048576);       // 16 MiB
    unsigned short* Hg  = (unsigned short*)(ws + 17825792);      // 16 MiB
    unsigned short* w1b = (unsigned short*)(ws + 34603008);      // 16 MiB
    unsigned short* Og  = (unsigned short*)(ws + 34603008);      // aliases w1b

    // Ag (expert-sorted bf16 activations) lives in d_out (16 MiB); d_out is
    // rewritten by combine_kernel at the end.
    unsigned short* Ag = (unsigned short*)d_out;

    convert_transpose_kernel<<<dim3(16, 16, 16), 256, 0, stream>>>(
        w1, w2, w1b, w2b, cnts);
    gate_kernel<<<dim3(N_TOKENS / 16), 256, 0, stream>>>(
        inp, gate_w, gate_b, cnts, emeta, stok);
    gather_kernel<<<dim3(N_TOKENS / 4), 256, 0, stream>>>(
        inp, cnts, emeta, Ag, tok2pos);
    ffn1_kernel<<<dim3(4096), 256, 0, stream>>>(Ag, w1b, b1, cnts, Hg);
    ffn2_kernel<<<dim3(4096), 256, 0, stream>>>(Hg, w2b, cnts, Og);
    combine_kernel<<<dim3(N_TOKENS / 4), 256, 0, stream>>>(
        Og, tok2pos, stok, emeta, b2, out);
}

// Round 10
// 224.495 us; speedup vs baseline: 2.0619x; 1.0294x over previous
//
#include <hip/hip_runtime.h>
#include <math.h>

#define N_TOKENS 4096
#define D_MODEL  1024
#define N_EXPERT 8
#define D_HIDDEN 1024
#define N_POS    8192   // N_TOKENS * TOP_K

typedef __bf16 bf16x8 __attribute__((ext_vector_type(8)));
typedef float  f32x4  __attribute__((ext_vector_type(4)));
typedef unsigned short u16x8 __attribute__((ext_vector_type(8)));

#define GLOBAL_AS __attribute__((address_space(1)))
#define LDS_AS    __attribute__((address_space(3)))

static __device__ __forceinline__ void async_ld16(const void* g, void* l) {
    __builtin_amdgcn_global_load_lds((GLOBAL_AS void*)g, (LDS_AS void*)l, 16, 0, 0);
}

static __device__ __forceinline__ unsigned short f2bf(float f) {
    unsigned int u = __builtin_bit_cast(unsigned int, f);
    u += 0x7fffu + ((u >> 16) & 1u);      // round-to-nearest-even
    return (unsigned short)(u >> 16);
}
static __device__ __forceinline__ unsigned int pack2(float a, float b) {
    return (unsigned int)f2bf(a) | ((unsigned int)f2bf(b) << 16);
}
static __device__ __forceinline__ float bflo(unsigned int u) {
    return __builtin_bit_cast(float, u << 16);
}
static __device__ __forceinline__ float bfhi(unsigned int u) {
    return __builtin_bit_cast(float, u & 0xffff0000u);
}

// ---------------------------------------------------------------------------
// Convert: mats 0..15 = w1/w2 fp32 -> bf16 TRANSPOSED [N][K] k-contig;
// mats 16..19 = inp quadrants fp32 -> bf16 straight copy-cast (token order).
// Also zeroes cnts.
// ---------------------------------------------------------------------------
__global__ __launch_bounds__(256) void convert_kernel(
    const float* __restrict__ w1, const float* __restrict__ w2,
    const float* __restrict__ inp,
    unsigned short* __restrict__ w1b, unsigned short* __restrict__ w2b,
    unsigned short* __restrict__ inp_bf, int* __restrict__ cnts)
{
    int tid = threadIdx.x;
    if (blockIdx.x == 0 && blockIdx.y == 0 && blockIdx.z == 0 && tid < 8)
        cnts[tid] = 0;
    int mat = blockIdx.z;
    int r0 = blockIdx.x * 64, c0 = blockIdx.y * 64;

    if (mat >= 16) {    // inp copy-cast, no transpose
        const float* src = inp + (size_t)(mat - 16) * 1048576;
        unsigned short* dst = inp_bf + (size_t)(mat - 16) * 1048576;
        #pragma unroll
        for (int i = 0; i < 4; ++i) {
            int r = (tid >> 4) + i * 16;
            float4 v = *(const float4*)(src + (size_t)(r0 + r) * 1024 + c0 + (tid & 15) * 4);
            uint2 u; u.x = pack2(v.x, v.y); u.y = pack2(v.z, v.w);
            *(uint2*)(dst + (size_t)(r0 + r) * 1024 + c0 + (tid & 15) * 4) = u;
        }
        return;
    }

    const float* src = (mat < 8) ? (w1 + (size_t)mat * 1048576)
                                 : (w2 + (size_t)(mat - 8) * 1048576);
    unsigned short* dst = (mat < 8) ? (w1b + (size_t)mat * 1048576)
                                    : (w2b + (size_t)(mat - 8) * 1048576);
    __shared__ float tile[64][68];
    #pragma unroll
    for (int i = 0; i < 4; ++i) {
        int r = (tid >> 4) + i * 16;
        float4 v = *(const float4*)(src + (size_t)(r0 + r) * 1024 + c0 + (tid & 15) * 4);
        *(float4*)&tile[r][(tid & 15) * 4] = v;
    }
    __syncthreads();
    int dr = tid >> 2;                     // dst row in tile (= src col)
    #pragma unroll
    for (int p = 0; p < 2; ++p) {
        int ch = (tid & 3) + p * 4;        // 8-elem chunk of the 64 src rows
        u16x8 o;
        #pragma unroll
        for (int j = 0; j < 8; ++j) o[j] = f2bf(tile[ch * 8 + j][dr]);
        *(u16x8*)(dst + (size_t)(c0 + dr) * 1024 + r0 + ch * 8) = o;
    }
}

// ---------------------------------------------------------------------------
// Gate: fp32-exact top-2 + softmax. Block-aggregated ranking.
// ---------------------------------------------------------------------------
__global__ __launch_bounds__(256) void gate_kernel(
    const float* __restrict__ inp, const float* __restrict__ gate_w,
    const float* __restrict__ gate_b, int* __restrict__ cnts,
    int* __restrict__ emeta, float* __restrict__ stok)
{
    __shared__ int bcnt[8], base[8];
    __shared__ int tinfo[16];   // e0 | e1<<4 | r0<<8 | r1<<20 (block-local)
    int tid = threadIdx.x, lane = tid & 63, wave = tid >> 6;
    if (tid < 8) bcnt[tid] = 0;
    __syncthreads();

    for (int t = 0; t < 4; ++t) {
        int ti = wave * 4 + t;
        int n  = blockIdx.x * 16 + ti;
        const float* ip = inp + (size_t)n * D_MODEL;
        float acc[8] = {0.f,0.f,0.f,0.f,0.f,0.f,0.f,0.f};
        for (int d0 = lane * 4; d0 < D_MODEL; d0 += 256) {
            float4 x = *(const float4*)(ip + d0);
            #pragma unroll
            for (int j = 0; j < 4; ++j) {
                float xv = (j == 0) ? x.x : (j == 1) ? x.y : (j == 2) ? x.z : x.w;
                float4 g0 = *(const float4*)(gate_w + (d0 + j) * 8);
                float4 g1 = *(const float4*)(gate_w + (d0 + j) * 8 + 4);
                acc[0] += xv * g0.x; acc[1] += xv * g0.y;
                acc[2] += xv * g0.z; acc[3] += xv * g0.w;
                acc[4] += xv * g1.x; acc[5] += xv * g1.y;
                acc[6] += xv * g1.z; acc[7] += xv * g1.w;
            }
        }
        #pragma unroll
        for (int off = 32; off > 0; off >>= 1)
            #pragma unroll
            for (int e = 0; e < 8; ++e)
                acc[e] += __shfl_xor(acc[e], off, 64);
        #pragma unroll
        for (int e = 0; e < 8; ++e) acc[e] += gate_b[e];

        // top-2; strictly-greater => lowest index wins ties (lax.top_k)
        int e0 = 0; float v0 = acc[0];
        #pragma unroll
        for (int e = 1; e < 8; ++e) if (acc[e] > v0) { v0 = acc[e]; e0 = e; }
        int e1 = -1; float v1 = -1e30f;
        #pragma unroll
        for (int e = 0; e < 8; ++e) if (e != e0 && acc[e] > v1) { v1 = acc[e]; e1 = e; }
        float tv = expf(v1 - v0);
        float s0 = 1.0f / (1.0f + tv);
        float s1 = tv / (1.0f + tv);

        if (lane == 0) {
            int r0 = atomicAdd(&bcnt[e0], 1);   // LDS atomic: block-local rank
            int r1 = atomicAdd(&bcnt[e1], 1);
            tinfo[ti] = e0 | (e1 << 4) | (r0 << 8) | (r1 << 20);
            stok[2 * n]     = s0;
            stok[2 * n + 1] = s1;
        }
    }
    __syncthreads();
    if (tid < 8) base[tid] = atomicAdd(&cnts[tid], bcnt[tid]);  // 8 globals/block
    __syncthreads();
    if (tid < 16) {
        int n = blockIdx.x * 16 + tid;
        unsigned int inf = (unsigned int)tinfo[tid];
        int e0 = inf & 15, e1 = (inf >> 4) & 15;
        int p0 = base[e0] + ((inf >> 8) & 4095);
        int p1 = base[e1] + (int)(inf >> 20);
        emeta[n] = e0 | (e1 << 4) | (p0 << 8) | (p1 << 20);
    }
}

// ---------------------------------------------------------------------------
// Plan: scatter position -> token map (replaces the full gather pass).
// ---------------------------------------------------------------------------
__global__ __launch_bounds__(256) void plan_kernel(
    const int* __restrict__ cnts, const int* __restrict__ emeta,
    int* __restrict__ pos2tok)
{
    int n = blockIdx.x * 256 + threadIdx.x;
    unsigned int em = (unsigned int)emeta[n];
    int e0 = em & 15, e1 = (em >> 4) & 15;
    int p0 = (em >> 8) & 4095, p1 = (int)(em >> 20);
    int off0 = 0, off1 = 0;
    #pragma unroll
    for (int e = 0; e < 8; ++e) {
        int c = cnts[e];
        off0 += (e < e0) ? c : 0;
        off1 += (e < e1) ? c : 0;
    }
    pos2tok[off0 + p0] = n;
    pos2tok[off1 + p1] = n;
}

// ---------------------------------------------------------------------------
// Grouped GEMM1 (exact R6 structure; A rows fetched via per-lane INDIRECT
// global_load_lds from token-ordered inp_bf using pos2tok — removes the
// 33MB gather pass; R1-verified per-lane-address staging pattern):
// Hg[pos] = gelu( inp_bf[tok(pos)] @ w1b[e]^T + b1[e] ),
// 128x64 tile, BK=64, 24 KB LDS, launch_bounds(256,4).
// ---------------------------------------------------------------------------
__global__ __launch_bounds__(256, 4) void ffn1_kernel(
    const unsigned short* __restrict__ inp_bf, const unsigned short* __restrict__ w1b,
    const float* __restrict__ b1, const int* __restrict__ cnts,
    const int* __restrict__ pos2tok, unsigned short* __restrict__ Hg)
{
    int bid = blockIdx.x;
    int e = bid & 7, nt = (bid >> 3) & 15, mt = bid >> 7;
    int off = 0, Ne = 0;
    #pragma unroll
    for (int i = 0; i < 8; ++i) {
        int c = cnts[i];
        off += (i < e) ? c : 0;
        Ne = (i == e) ? c : Ne;
    }
    int m0 = mt * 128;
    if (m0 >= Ne) return;
    int n0 = nt * 64;

    __shared__ unsigned short As[2 * 128 * 32];   // [half][row][32] 16 KB
    __shared__ unsigned short Bs[2 * 64 * 32];    // [half][row][32]  8 KB
    __shared__ int rowtok[128];

    int tid = threadIdx.x, lane = tid & 63, wave = tid >> 6;
    int lrow = lane >> 2, lchunk = lane & 3;
    int csw8 = (lchunk ^ ((lrow >> 1) & 3)) * 8;

    if (tid < 128) {
        int r = m0 + tid;
        if (r >= Ne) r = Ne - 1;              // dup last valid row; masked later
        rowtok[tid] = pos2tok[off + r];
    }
    __syncthreads();

    const unsigned short* aS0 =
        inp_bf + (size_t)rowtok[wave * 32 + lrow] * D_MODEL + csw8;
    const unsigned short* aS1 =
        inp_bf + (size_t)rowtok[wave * 32 + 16 + lrow] * D_MODEL + csw8;
    const unsigned short* bS = w1b + (size_t)e * D_MODEL * D_HIDDEN
                             + (size_t)(n0 + wave * 16 + lrow) * D_MODEL + csw8;
    unsigned short* aD0 = &As[(wave * 32) * 32];
    unsigned short* aD1 = &As[(wave * 32 + 16) * 32];
    unsigned short* bD  = &Bs[(wave * 16) * 32];

    f32x4 acc[4][2] = {};
    int wm = (wave & 1) * 64, wn = ((wave >> 1) & 1) * 32;
    int lane15 = lane & 15, quad = lane >> 4;
    int fro = (quad ^ ((lane15 >> 1) & 3)) * 8;

    for (int k0 = 0; k0 < D_MODEL; k0 += 64) {
        #pragma unroll
        for (int h = 0; h < 2; ++h) {
            int ko = k0 + h * 32;
            async_ld16(aS0 + ko, aD0 + h * 4096);
            async_ld16(aS1 + ko, aD1 + h * 4096);
            async_ld16(bS  + ko, bD  + h * 2048);
        }
        __syncthreads();
        #pragma unroll
        for (int h = 0; h < 2; ++h) {
            bf16x8 af[4], bf[2];
            #pragma unroll
            for (int t = 0; t < 4; ++t)
                af[t] = *(const bf16x8*)&As[h * 4096 + (wm + t * 16 + lane15) * 32 + fro];
            #pragma unroll
            for (int t = 0; t < 2; ++t)
                bf[t] = *(const bf16x8*)&Bs[h * 2048 + (wn + t * 16 + lane15) * 32 + fro];
            #pragma unroll
            for (int i = 0; i < 4; ++i)
                #pragma unroll
                for (int j = 0; j < 2; ++j)
                    acc[i][j] = __builtin_amdgcn_mfma_f32_16x16x32_bf16(
                        af[i], bf[j], acc[i][j], 0, 0, 0);
        }
        if (k0 + 64 < D_MODEL) __syncthreads();
    }

    const float* bexp = b1 + (size_t)e * D_HIDDEN;
    #pragma unroll
    for (int j = 0; j < 2; ++j) {
        int gcol = n0 + wn + j * 16 + lane15;
        float bv = bexp[gcol];
        #pragma unroll
        for (int i = 0; i < 4; ++i) {
            int rowb = wm + i * 16 + quad * 4;
            #pragma unroll
            for (int r = 0; r < 4; ++r) {
                int row = rowb + r;
                if (m0 + row < Ne) {
                    float x = acc[i][j][r] + bv;
                    float gv = 0.5f * x * (1.0f + erff(x * 0.70710678118654752f));
                    Hg[(size_t)(off + m0 + row) * D_HIDDEN + gcol] = f2bf(gv);
                }
            }
        }
    }
}

// ---------------------------------------------------------------------------
// Grouped GEMM2 (exact R6): Og[pos] = Hg[pos] @ w2b[e]^T
// ---------------------------------------------------------------------------
__global__ __launch_bounds__(256, 4) void ffn2_kernel(
    const unsigned short* __restrict__ Hg, const unsigned short* __restrict__ w2b,
    const int* __restrict__ cnts, unsigned short* __restrict__ Og)
{
    int bid = blockIdx.x;
    int e = bid & 7, nt = (bid >> 3) & 15, mt = bid >> 7;
    int off = 0, Ne = 0;
    #pragma unroll
    for (int i = 0; i < 8; ++i) {
        int c = cnts[i];
        off += (i < e) ? c : 0;
        Ne = (i == e) ? c : Ne;
    }
    int m0 = mt * 128;
    if (m0 >= Ne) return;
    int n0 = nt * 64;

    __shared__ unsigned short As[2 * 128 * 32];
    __shared__ unsigned short Bs[2 * 64 * 32];

    int tid = threadIdx.x, lane = tid & 63, wave = tid >> 6;
    int lrow = lane >> 2, lchunk = lane & 3;
    int csw8 = (lchunk ^ ((lrow >> 1) & 3)) * 8;

    int ga0 = off + m0 + wave * 32 + lrow;
    int ga1 = ga0 + 16;
    if (ga0 >= N_POS) ga0 = N_POS - 1;
    if (ga1 >= N_POS) ga1 = N_POS - 1;
    const unsigned short* aS0 = Hg + (size_t)ga0 * D_HIDDEN + csw8;
    const unsigned short* aS1 = Hg + (size_t)ga1 * D_HIDDEN + csw8;
    const unsigned short* bS = w2b + (size_t)e * D_HIDDEN * D_MODEL
                             + (size_t)(n0 + wave * 16 + lrow) * D_HIDDEN + csw8;
    unsigned short* aD0 = &As[(wave * 32) * 32];
    unsigned short* aD1 = &As[(wave * 32 + 16) * 32];
    unsigned short* bD  = &Bs[(wave * 16) * 32];

    f32x4 acc[4][2] = {};
    int wm = (wave & 1) * 64, wn = ((wave >> 1) & 1) * 32;
    int lane15 = lane & 15, quad = lane >> 4;
    int fro = (quad ^ ((lane15 >> 1) & 3)) * 8;

    for (int k0 = 0; k0 < D_HIDDEN; k0 += 64) {
        #pragma unroll
        for (int h = 0; h < 2; ++h) {
            int ko = k0 + h * 32;
            async_ld16(aS0 + ko, aD0 + h * 4096);
            async_ld16(aS1 + ko, aD1 + h * 4096);
            async_ld16(bS  + ko, bD  + h * 2048);
        }
        __syncthreads();
        #pragma unroll
        for (int h = 0; h < 2; ++h) {
            bf16x8 af[4], bf[2];
            #pragma unroll
            for (int t = 0; t < 4; ++t)
                af[t] = *(const bf16x8*)&As[h * 4096 + (wm + t * 16 + lane15) * 32 + fro];
            #pragma unroll
            for (int t = 0; t < 2; ++t)
                bf[t] = *(const bf16x8*)&Bs[h * 2048 + (wn + t * 16 + lane15) * 32 + fro];
            #pragma unroll
            for (int i = 0; i < 4; ++i)
                #pragma unroll
                for (int j = 0; j < 2; ++j)
                    acc[i][j] = __builtin_amdgcn_mfma_f32_16x16x32_bf16(
                        af[i], bf[j], acc[i][j], 0, 0, 0);
        }
        if (k0 + 64 < D_HIDDEN) __syncthreads();
    }

    #pragma unroll
    for (int j = 0; j < 2; ++j) {
        int gcol = n0 + wn + j * 16 + lane15;
        #pragma unroll
        for (int i = 0; i < 4; ++i) {
            int rowb = wm + i * 16 + quad * 4;
            #pragma unroll
            for (int r = 0; r < 4; ++r) {
                int row = rowb + r;
                if (m0 + row < Ne) {
                    Og[(size_t)(off + m0 + row) * D_MODEL + gcol] =
                        f2bf(acc[i][j][r]);
                }
            }
        }
    }
}

// ---------------------------------------------------------------------------
// Combine: out[n] = s0*(Og[pos0]+b2[e0]) + s1*(Og[pos1]+b2[e1]);
// positions derived from emeta + cnts prefix (no tok2pos array).
// ---------------------------------------------------------------------------
__global__ __launch_bounds__(256) void combine_kernel(
    const unsigned short* __restrict__ Og, const int* __restrict__ cnts,
    const int* __restrict__ emeta, const float* __restrict__ stok,
    const float* __restrict__ b2, float* __restrict__ out)
{
    int lane = threadIdx.x & 63, wave = threadIdx.x >> 6;
    int n = blockIdx.x * 4 + wave;
    unsigned int em = (unsigned int)emeta[n];
    int e0 = em & 15, e1 = (em >> 4) & 15;
    int p0 = (em >> 8) & 4095, p1 = (int)(em >> 20);
    int off0 = 0, off1 = 0;
    #pragma unroll
    for (int e = 0; e < 8; ++e) {
        int c = cnts[e];
        off0 += (e < e0) ? c : 0;
        off1 += (e < e1) ? c : 0;
    }
    int pos0 = off0 + p0, pos1 = off1 + p1;
    float s0 = stok[2 * n], s1 = stok[2 * n + 1];
    const unsigned short* o0 = Og + (size_t)pos0 * D_MODEL;
    const unsigned short* o1 = Og + (size_t)pos1 * D_MODEL;
    const float* bA = b2 + (size_t)e0 * D_MODEL;
    const float* bB = b2 + (size_t)e1 * D_MODEL;
    float* op = out + (size_t)n * D_MODEL;
    for (int d = lane * 4; d < D_MODEL; d += 256) {
        uint2 u0 = *(const uint2*)(o0 + d);
        uint2 u1 = *(const uint2*)(o1 + d);
        float4 xa = *(const float4*)(bA + d);
        float4 xb = *(const float4*)(bB + d);
        float4 r;
        r.x = s0 * (bflo(u0.x) + xa.x) + s1 * (bflo(u1.x) + xb.x);
        r.y = s0 * (bfhi(u0.x) + xa.y) + s1 * (bfhi(u1.x) + xb.y);
        r.z = s0 * (bflo(u0.y) + xa.z) + s1 * (bflo(u1.y) + xb.z);
        r.w = s0 * (bfhi(u0.y) + xa.w) + s1 * (bfhi(u1.y) + xb.w);
        *(float4*)(op + d) = r;
    }
}

// ---------------------------------------------------------------------------
extern "C" void kernel_launch(void* const* d_in, const int* in_sizes, int n_in,
                              void* d_out, int out_size, void* d_ws, size_t ws_size,
                              hipStream_t stream) {
    const float* inp    = (const float*)d_in[0];
    const float* gate_w = (const float*)d_in[1];
    const float* gate_b = (const float*)d_in[2];
    const float* w1     = (const float*)d_in[3];
    const float* b1     = (const float*)d_in[4];
    const float* w2     = (const float*)d_in[5];
    const float* b2     = (const float*)d_in[6];
    float* out = (float*)d_out;

    // ws layout (Og aliases w1b: w1b dead after ffn1, Og written in ffn2).
    char* ws = (char*)d_ws;
    int*   cnts    = (int*)  (ws);                               // 128 B
    int*   emeta   = (int*)  (ws + 4096);                        // 16 KB
    float* stok    = (float*)(ws + 65536);                       // 32 KB
    int*   pos2tok = (int*)  (ws + 131072);                      // 32 KB
    unsigned short* w2b = (unsigned short*)(ws + 1048576);       // 16 MiB
    unsigned short* Hg  = (unsigned short*)(ws + 17825792);      // 16 MiB
    unsigned short* w1b = (unsigned short*)(ws + 34603008);      // 16 MiB
    unsigned short* Og  = (unsigned short*)(ws + 34603008);      // aliases w1b

    // inp_bf (token-ordered bf16 activations) lives in d_out (16 MiB); read
    // by ffn1 only; combine rewrites d_out at the end.
    unsigned short* inp_bf = (unsigned short*)d_out;

    convert_kernel<<<dim3(16, 16, 20), 256, 0, stream>>>(
        w1, w2, inp, w1b, w2b, inp_bf, cnts);
    gate_kernel<<<dim3(N_TOKENS / 16), 256, 0, stream>>>(
        inp, gate_w, gate_b, cnts, emeta, stok);
    plan_kernel<<<dim3(N_TOKENS / 256), 256, 0, stream>>>(cnts, emeta, pos2tok);
    ffn1_kernel<<<dim3(4096), 256, 0, stream>>>(
        inp_bf, w1b, b1, cnts, pos2tok, Hg);
    ffn2_kernel<<<dim3(4096), 256, 0, stream>>>(Hg, w2b, cnts, Og);
    combine_kernel<<<dim3(N_TOKENS / 4), 256, 0, stream>>>(
        Og, cnts, emeta, stok, b2, out);
}